// Round 6
// baseline (283.283 us; speedup 1.0000x reference)
//
#include <hip/hip_runtime.h>
#include <math.h>

// Problem constants (from reference setup_inputs)
#define BBATCH 16
#define NPTS   4096
#define MPTS   1024
#define C1c    128
#define C2c    256
#define CINc   384
#define H1c    256
#define H2c    128
#define TN     64

typedef _Float16 f16x8 __attribute__((ext_vector_type(8)));
typedef _Float16 f16x4 __attribute__((ext_vector_type(4)));
typedef float    f32x4 __attribute__((ext_vector_type(4)));

#define LDXc 408   // f16 stride, s_X rows [64 n][384 k] (816 B rows)
#define LDH  264   // f16 stride, s_H rows [64 n][256 k]
#define SMEM_BYTES 52224   // max(xyz2 12288, s_X 52224, s_H 33792); 3 blocks/CU

// ws layout (f16 elements)
#define WS_P2H  0
#define WS_W1H  (BBATCH * C2c * MPTS)            // 4194304
#define WS_W2H  (WS_W1H + H1c * CINc)            // +98304
#define WS_F16_TOTAL (WS_W2H + H2c * H1c)        // 4325376 elems = 8650752 B

// ---------------------------------------------------------------------------
// pre-pass: convert p2 / W1 / W2 to f16 into workspace
__global__ __launch_bounds__(256) void cvt_f16(
    const float* __restrict__ p2, const float* __restrict__ W1,
    const float* __restrict__ W2, _Float16* __restrict__ ws)
{
    const int NP2 = BBATCH * C2c * MPTS / 4;   // 1048576 float4s
    const int NW1 = H1c * CINc / 4;            // 24576
    const int i = blockIdx.x * 256 + threadIdx.x;
    float4 v; _Float16* dst;
    if (i < NP2)            { v = ((const float4*)p2)[i];            dst = ws + WS_P2H + (size_t)i * 4; }
    else if (i < NP2 + NW1) { int j = i - NP2; v = ((const float4*)W1)[j]; dst = ws + WS_W1H + (size_t)j * 4; }
    else                    { int j = i - NP2 - NW1; v = ((const float4*)W2)[j]; dst = ws + WS_W2H + (size_t)j * 4; }
    f16x4 h;
    h[0] = (_Float16)v.x; h[1] = (_Float16)v.y; h[2] = (_Float16)v.z; h[3] = (_Float16)v.w;
    *(f16x4*)dst = h;
}

// ---------------------------------------------------------------------------
// Barrier-free phase A: wave grid 2c x 2n; wave owns 128 c-rows x 32 n-cols.
//   A = p2h rows direct from L2 (f16x8 frags, 2x duplication across waves).
//   B = inv generated IN REGISTERS in B-frag layout (lane l16 = its query n,
//       k = quad*8+j = m) — 2x redundant across c-waves, zero LDS, zero sync.
//   S[n] = ones-A MFMA accumulated alongside -> normalization is wave-local.
// Phases B/C as in R3 (they are small); only 5 barriers in the whole kernel.
template <bool F16P>
__global__ __launch_bounds__(256, 3) void fp_mfma5(
    const float* __restrict__ xyz1, const float* __restrict__ xyz2,
    const float* __restrict__ p1,   const float* __restrict__ p2,
    const float* __restrict__ W1,   const float* __restrict__ b1v,
    const float* __restrict__ W2,   const float* __restrict__ b2v,
    const _Float16* __restrict__ p2h, const _Float16* __restrict__ W1h,
    const _Float16* __restrict__ W2h,
    float* __restrict__ out)
{
    __shared__ __align__(16) char smem[SMEM_BYTES];
    float*    s_xyz2 = (float*)smem;       // phase A only
    _Float16* s_X    = (_Float16*)smem;    // phase B (overlays xyz2 after barrier)
    _Float16* s_H    = (_Float16*)smem;    // phase C

    const int tid  = threadIdx.x;
    const int w    = tid >> 6;    // wave 0..3
    const int L    = tid & 63;
    const int quad = L >> 4;
    const int l16  = L & 15;
    const int wc   = w & 1;       // c-half (phase A)
    const int wn   = w >> 1;      // n-half (phase A)

    // XCD swizzle: each XCD sees 2 batches -> p2h working set (1 MB f16) L2-resident
    const int id = blockIdx.x;
    const int b  = (id & 7) * 2 + ((id >> 3) & 1);
    const int n0 = (id >> 4) * TN;

    const float*    __restrict__ p2b  = p2  + (size_t)b * C2c * MPTS;
    const _Float16* __restrict__ p2hb = F16P ? (p2h + (size_t)b * C2c * MPTS) : (const _Float16*)nullptr;
    const float*    __restrict__ z2b  = xyz2 + (size_t)b * MPTS * 3;

    // stage xyz2 (12 KB, f32x4: 768 vectors over 256 threads)
    for (int i = tid; i < MPTS * 3 / 4; i += 256)
        ((f32x4*)s_xyz2)[i] = ((const f32x4*)z2b)[i];

    // this lane's two query points: n = n0 + wn*32 + nt*16 + l16
    float qx[2], qy[2], qz[2];
    #pragma unroll
    for (int nt = 0; nt < 2; ++nt) {
        const float* q = xyz1 + ((size_t)b * NPTS + n0 + wn * 32 + nt * 16 + l16) * 3;
        qx[nt] = q[0]; qy[nt] = q[1]; qz[nt] = q[2];
    }

    f32x4 acc[8][2];   // [ct][nt]: row c = wc*128+ct*16+quad*4+r, col n = wn*32+nt*16+l16
    #pragma unroll
    for (int ct = 0; ct < 8; ++ct)
        #pragma unroll
        for (int nt = 0; nt < 2; ++nt)
            acc[ct][nt] = (f32x4){0.f, 0.f, 0.f, 0.f};
    f32x4 accS[2];
    accS[0] = (f32x4){0.f, 0.f, 0.f, 0.f};
    accS[1] = (f32x4){0.f, 0.f, 0.f, 0.f};

    f16x8 onesv;
    #pragma unroll
    for (int i = 0; i < 8; ++i) onesv[i] = (_Float16)1.0f;

    // A-frag base: c-row = wc*128 + (g*4+ct)*16 + l16, k = quad*8
    const _Float16* aph = F16P ? (p2hb + (size_t)(wc * 128 + l16) * MPTS + quad * 8) : (const _Float16*)nullptr;
    const float*    apf = p2b + (size_t)(wc * 128 + l16) * MPTS + quad * 8;

    __syncthreads();   // xyz2 staged — LAST barrier until phase A completes

    #pragma unroll 2
    for (int s = 0; s < 32; ++s) {
        // ---- generate B-frags in registers (lane = query n, k = m) ----
        f32x4 zr[6];
        {
            const float* zp = s_xyz2 + (s * 32 + quad * 8) * 3;   // broadcast within quad-group
            #pragma unroll
            for (int j = 0; j < 6; ++j) zr[j] = ((const f32x4*)zp)[j];
        }
        const float* zv = (const float*)zr;
        f16x8 bf[2];
        #pragma unroll
        for (int i = 0; i < 8; ++i) {
            const float mx = zv[3 * i + 0];
            const float my = zv[3 * i + 1];
            const float mz = zv[3 * i + 2];
            #pragma unroll
            for (int nt = 0; nt < 2; ++nt) {
                const float dx = qx[nt] - mx;
                const float dy = qy[nt] - my;
                const float dz = qz[nt] - mz;
                const float d2 = fmaf(dx, dx, fmaf(dy, dy, fmaf(dz, dz, 1e-12f)));
                bf[nt][i] = (_Float16)__builtin_amdgcn_rsqf(d2);
            }
        }
        // S[n] via ones-A MFMA (all D-rows equal sum_m inv[m][n])
        #pragma unroll
        for (int nt = 0; nt < 2; ++nt)
            accS[nt] = __builtin_amdgcn_mfma_f32_16x16x32_f16(onesv, bf[nt], accS[nt], 0, 0, 0);

        // ---- A-frags direct from L2, two groups of 4 c-tiles ----
        #pragma unroll
        for (int g = 0; g < 2; ++g) {
            f16x8 af[4];
            if (F16P) {
                const _Float16* ap = aph + s * 32;
                #pragma unroll
                for (int ct = 0; ct < 4; ++ct)
                    af[ct] = *(const f16x8*)(ap + (size_t)(g * 4 + ct) * (16 * MPTS));
            } else {
                const float* ap = apf + s * 32;
                #pragma unroll
                for (int ct = 0; ct < 4; ++ct) {
                    const float4 a0 = *(const float4*)(ap + (size_t)(g * 4 + ct) * (16 * MPTS));
                    const float4 a1 = *(const float4*)(ap + (size_t)(g * 4 + ct) * (16 * MPTS) + 4);
                    f16x8 h;
                    h[0] = (_Float16)a0.x; h[1] = (_Float16)a0.y; h[2] = (_Float16)a0.z; h[3] = (_Float16)a0.w;
                    h[4] = (_Float16)a1.x; h[5] = (_Float16)a1.y; h[6] = (_Float16)a1.z; h[7] = (_Float16)a1.w;
                    af[ct] = h;
                }
            }
            #pragma unroll
            for (int ct = 0; ct < 4; ++ct)
                #pragma unroll
                for (int nt = 0; nt < 2; ++nt)
                    acc[g * 4 + ct][nt] =
                        __builtin_amdgcn_mfma_f32_16x16x32_f16(af[ct], bf[nt], acc[g * 4 + ct][nt], 0, 0, 0);
        }
    }

    // wave-local normalization (accS rows identical; col n = l16 matches acc cols)
    const float rn0 = 1.0f / accS[0][0];
    const float rn1 = 1.0f / accS[1][0];

    __syncthreads();   // all waves done reading s_xyz2 -> safe to overlay s_X

    // interp -> s_X[n][128 + c]
    #pragma unroll
    for (int ct = 0; ct < 8; ++ct)
        #pragma unroll
        for (int nt = 0; nt < 2; ++nt) {
            const f32x4 v = acc[ct][nt];
            const float r = nt ? rn1 : rn0;
            f16x4 hv;
            hv[0] = (_Float16)(v[0] * r);
            hv[1] = (_Float16)(v[1] * r);
            hv[2] = (_Float16)(v[2] * r);
            hv[3] = (_Float16)(v[3] * r);
            *(f16x4*)(&s_X[(wn * 32 + nt * 16 + l16) * LDXc + 128 + wc * 128 + ct * 16 + quad * 4]) = hv;
        }
    // p1 -> s_X[n][c], c in [0,128)
    {
        const float* p1b = p1 + (size_t)b * C1c * NPTS + n0;
        #pragma unroll
        for (int cc = 0; cc < 8; ++cc) {
            const int c = w * 32 + cc * 4;
            f16x4 v;
            v[0] = (_Float16)p1b[(size_t)(c + 0) * NPTS + L];
            v[1] = (_Float16)p1b[(size_t)(c + 1) * NPTS + L];
            v[2] = (_Float16)p1b[(size_t)(c + 2) * NPTS + L];
            v[3] = (_Float16)p1b[(size_t)(c + 3) * NPTS + L];
            *(f16x4*)(&s_X[L * LDXc + c]) = v;
        }
    }
    __syncthreads();   // x matrix complete

    // ---------------- Phase B: h = relu(W1 @ x + b1), K=384 ----------------
    f32x4 hacc[4][4];
    #pragma unroll
    for (int ct = 0; ct < 4; ++ct)
        #pragma unroll
        for (int nt = 0; nt < 4; ++nt)
            hacc[ct][nt] = (f32x4){0.f, 0.f, 0.f, 0.f};

    #pragma unroll 2
    for (int kc = 0; kc < 12; ++kc) {
        f16x8 af[4];
        if (F16P) {
            const _Float16* wp = W1h + (size_t)(w * 64 + l16) * CINc + kc * 32 + quad * 8;
            #pragma unroll
            for (int ct = 0; ct < 4; ++ct) af[ct] = *(const f16x8*)(wp + ct * (16 * CINc));
        } else {
            const float* wp = W1 + (size_t)(w * 64 + l16) * CINc + kc * 32 + quad * 8;
            #pragma unroll
            for (int ct = 0; ct < 4; ++ct) {
                const float4 a0 = *(const float4*)(wp + ct * (16 * CINc));
                const float4 a1 = *(const float4*)(wp + ct * (16 * CINc) + 4);
                f16x8 h;
                h[0] = (_Float16)a0.x; h[1] = (_Float16)a0.y; h[2] = (_Float16)a0.z; h[3] = (_Float16)a0.w;
                h[4] = (_Float16)a1.x; h[5] = (_Float16)a1.y; h[6] = (_Float16)a1.z; h[7] = (_Float16)a1.w;
                af[ct] = h;
            }
        }
        #pragma unroll
        for (int nt = 0; nt < 4; ++nt) {
            const f16x8 bf = *(const f16x8*)(&s_X[(nt * 16 + l16) * LDXc + kc * 32 + quad * 8]);
            #pragma unroll
            for (int ct = 0; ct < 4; ++ct)
                hacc[ct][nt] = __builtin_amdgcn_mfma_f32_16x16x32_f16(af[ct], bf, hacc[ct][nt], 0, 0, 0);
        }
    }

    __syncthreads();   // all s_X reads done before overlaying s_H

    // bias + relu + stage h -> s_H[n][o1]  (wave w owns o1 rows [w*64, +64))
    {
        f32x4 bb[4];
        #pragma unroll
        for (int ct = 0; ct < 4; ++ct)
            bb[ct] = *(const f32x4*)(b1v + w * 64 + ct * 16 + quad * 4);
        #pragma unroll
        for (int ct = 0; ct < 4; ++ct)
            #pragma unroll
            for (int nt = 0; nt < 4; ++nt) {
                const f32x4 v = hacc[ct][nt];
                f16x4 hv;
                hv[0] = (_Float16)fmaxf(v[0] + bb[ct][0], 0.f);
                hv[1] = (_Float16)fmaxf(v[1] + bb[ct][1], 0.f);
                hv[2] = (_Float16)fmaxf(v[2] + bb[ct][2], 0.f);
                hv[3] = (_Float16)fmaxf(v[3] + bb[ct][3], 0.f);
                *(f16x4*)(&s_H[(nt * 16 + l16) * LDH + w * 64 + ct * 16 + quad * 4]) = hv;
            }
    }
    __syncthreads();

    // ---------------- Phase C: out = relu(W2 @ h + b2), K=256 ----------------
    f32x4 oacc[2][4];
    #pragma unroll
    for (int ct = 0; ct < 2; ++ct)
        #pragma unroll
        for (int nt = 0; nt < 4; ++nt)
            oacc[ct][nt] = (f32x4){0.f, 0.f, 0.f, 0.f};

    #pragma unroll 2
    for (int oc = 0; oc < 8; ++oc) {
        f16x8 af2[2];
        if (F16P) {
            const _Float16* wp = W2h + (size_t)(w * 32 + l16) * H1c + oc * 32 + quad * 8;
            #pragma unroll
            for (int ct = 0; ct < 2; ++ct) af2[ct] = *(const f16x8*)(wp + ct * (16 * H1c));
        } else {
            const float* wp = W2 + (size_t)(w * 32 + l16) * H1c + oc * 32 + quad * 8;
            #pragma unroll
            for (int ct = 0; ct < 2; ++ct) {
                const float4 a0 = *(const float4*)(wp + ct * (16 * H1c));
                const float4 a1 = *(const float4*)(wp + ct * (16 * H1c) + 4);
                f16x8 h;
                h[0] = (_Float16)a0.x; h[1] = (_Float16)a0.y; h[2] = (_Float16)a0.z; h[3] = (_Float16)a0.w;
                h[4] = (_Float16)a1.x; h[5] = (_Float16)a1.y; h[6] = (_Float16)a1.z; h[7] = (_Float16)a1.w;
                af2[ct] = h;
            }
        }
        #pragma unroll
        for (int nt = 0; nt < 4; ++nt) {
            const f16x8 bf = *(const f16x8*)(&s_H[(nt * 16 + l16) * LDH + oc * 32 + quad * 8]);
            #pragma unroll
            for (int ct = 0; ct < 2; ++ct)
                oacc[ct][nt] = __builtin_amdgcn_mfma_f32_16x16x32_f16(af2[ct], bf, oacc[ct][nt], 0, 0, 0);
        }
    }

    // epilogue: bias + relu + store
    {
        f32x4 bb2[2];
        #pragma unroll
        for (int ct = 0; ct < 2; ++ct)
            bb2[ct] = *(const f32x4*)(b2v + w * 32 + ct * 16 + quad * 4);
        #pragma unroll
        for (int ct = 0; ct < 2; ++ct)
            #pragma unroll
            for (int nt = 0; nt < 4; ++nt) {
                float* op = out + ((size_t)b * H2c + w * 32 + ct * 16 + quad * 4) * NPTS
                                + n0 + nt * 16 + l16;
                #pragma unroll
                for (int j = 0; j < 4; ++j)
                    op[(size_t)j * NPTS] = fmaxf(oacc[ct][nt][j] + bb2[ct][j], 0.f);
            }
    }
}

extern "C" void kernel_launch(void* const* d_in, const int* in_sizes, int n_in,
                              void* d_out, int out_size, void* d_ws, size_t ws_size,
                              hipStream_t stream) {
    (void)in_sizes; (void)n_in; (void)out_size;
    const float* xyz1 = (const float*)d_in[0];
    const float* xyz2 = (const float*)d_in[1];
    const float* p1   = (const float*)d_in[2];
    const float* p2   = (const float*)d_in[3];
    const float* W1   = (const float*)d_in[4];
    const float* b1   = (const float*)d_in[5];
    const float* W2   = (const float*)d_in[6];
    const float* b2   = (const float*)d_in[7];
    float* out = (float*)d_out;

    const bool useh = (ws_size >= (size_t)WS_F16_TOTAL * 2);
    dim3 grid(BBATCH * (NPTS / TN));   // 1024 blocks
    dim3 block(256);
    if (useh) {
        _Float16* ws = (_Float16*)d_ws;
        const int ncvt = (BBATCH * C2c * MPTS + H1c * CINc + H2c * H1c) / 4;  // 1081344
        cvt_f16<<<dim3(ncvt / 256), dim3(256), 0, stream>>>(p2, W1, W2, ws);
        fp_mfma5<true><<<grid, block, 0, stream>>>(xyz1, xyz2, p1, p2, W1, b1, W2, b2,
                                                   ws + WS_P2H, ws + WS_W1H, ws + WS_W2H, out);
    } else {
        fp_mfma5<false><<<grid, block, 0, stream>>>(xyz1, xyz2, p1, p2, W1, b1, W2, b2,
                                                    nullptr, nullptr, nullptr, out);
    }
}

// Round 7
// 177.791 us; speedup vs baseline: 1.5934x; 1.5934x over previous
//
#include <hip/hip_runtime.h>
#include <math.h>

// Problem constants (from reference setup_inputs)
#define BBATCH 16
#define NPTS   4096
#define MPTS   1024
#define C1c    128
#define C2c    256
#define CINc   384
#define H1c    256
#define H2c    128
#define TN     64

typedef _Float16 f16x8 __attribute__((ext_vector_type(8)));
typedef _Float16 f16x4 __attribute__((ext_vector_type(4)));
typedef float    f32x4 __attribute__((ext_vector_type(4)));

#define LDI  40    // f16 stride, s_inv rows [64 n][32 m] (80 B rows, 20-bank rotation)
#define LDXc 408   // f16 stride, s_X rows [64 n][384 k]
#define LDH  264   // f16 stride, s_H rows [64 n][256 k]

// shared memory union (bytes)
#define OFF_INV   0                    // 2 x 64*LDI*2 = 10240 B  (phase A dbuf)
#define OFF_RED   10240                // 1024 B s_red[256]
#define OFF_RECIP 52224                // 256 B s_recip (beyond s_X so it survives overlay)
#define SMEM_BYTES 52480               // s_X 52224 dominates; 3 blocks/CU (157440 <= 163840)

// ws layout (f16 elements) — all operands PRE-SWIZZLED into MFMA-frag order:
//   p2s: frag t = ((b*32+s)*16 + wt)*64 + lane, elem i: (c=wt*16+(lane&15), m=s*32+(lane>>4)*8+i)
//   W1s: frag u = (wt*12 + kc)*64 + lane:             (o=wt*16+(lane&15), k=kc*32+(lane>>4)*8+i)
//   W2s: frag v = (wt2*8 + oc)*64 + lane:             (o=wt2*16+(lane&15), k=oc*32+(lane>>4)*8+i)
#define NFRAG_P2  (BBATCH * 32 * 16 * 64)        // 524288 frags
#define NFRAG_W1  (16 * 12 * 64)                 // 12288
#define NFRAG_W2  (8 * 8 * 64)                   // 4096
#define WS_P2S  0
#define WS_W1S  (NFRAG_P2 * 8)                   // 4194304 f16
#define WS_W2S  (WS_W1S + NFRAG_W1 * 8)          // +98304
#define WS_F16_TOTAL (WS_W2S + NFRAG_W2 * 8)     // 4325376 f16 = 8650752 B

// ---------------------------------------------------------------------------
// pre-pass: convert + swizzle p2 / W1 / W2 into fragment-contiguous f16
__global__ __launch_bounds__(256) void cvt_swz(
    const float* __restrict__ p2, const float* __restrict__ W1,
    const float* __restrict__ W2, _Float16* __restrict__ ws)
{
    const int t = blockIdx.x * 256 + threadIdx.x;   // one fragment (8 f16) per thread
    const float* src;
    _Float16* dst;
    if (t < NFRAG_P2) {
        const int lane = t & 63, wt = (t >> 6) & 15, s = (t >> 10) & 31, b = t >> 15;
        const int c = wt * 16 + (lane & 15);
        const int m = s * 32 + (lane >> 4) * 8;
        src = p2 + ((size_t)(b * C2c + c)) * MPTS + m;
        dst = ws + WS_P2S + (size_t)t * 8;
    } else if (t < NFRAG_P2 + NFRAG_W1) {
        const int u = t - NFRAG_P2;
        const int lane = u & 63, kc = (u >> 6) % 12, wt = (u >> 6) / 12;
        const int o = wt * 16 + (lane & 15);
        const int k = kc * 32 + (lane >> 4) * 8;
        src = W1 + (size_t)o * CINc + k;
        dst = ws + WS_W1S + (size_t)u * 8;
    } else {
        const int v = t - NFRAG_P2 - NFRAG_W1;
        const int lane = v & 63, oc = (v >> 6) & 7, wt2 = v >> 9;
        const int o = wt2 * 16 + (lane & 15);
        const int k = oc * 32 + (lane >> 4) * 8;
        src = W2 + (size_t)o * H1c + k;
        dst = ws + WS_W2S + (size_t)v * 8;
    }
    const float4 a0 = *(const float4*)(src);
    const float4 a1 = *(const float4*)(src + 4);
    f16x8 h;
    h[0] = (_Float16)a0.x; h[1] = (_Float16)a0.y; h[2] = (_Float16)a0.z; h[3] = (_Float16)a0.w;
    h[4] = (_Float16)a1.x; h[5] = (_Float16)a1.y; h[6] = (_Float16)a1.z; h[7] = (_Float16)a1.w;
    *(f16x8*)dst = h;
}

// ---------------------------------------------------------------------------
// Phase A: c-partitioned waves (wave w owns c rows [w*64,+64) for all 64 n).
//   A = p2s frags, CONTIGUOUS 1KB/wave loads from L2, register-dbuf 1 step ahead.
//   B = inv chunk, generated once (8 rsq/thread/step) -> LDS dbuf, 1 barrier/step.
//   S[n] scalar partials alongside gen + one cross-wave reduce.
// Phase B: h = relu(W1 @ concat(p1, U/S) + b1): A = W1s frags (contiguous), B = s_X.
// Phase C: out = relu(W2 @ h + b2):             A = W2s frags (contiguous), B = s_H.
template <bool F16P>
__global__ __launch_bounds__(256, 3) void fp_mfma6(
    const float* __restrict__ xyz1, const float* __restrict__ xyz2,
    const float* __restrict__ p1,   const float* __restrict__ p2,
    const float* __restrict__ W1,   const float* __restrict__ b1v,
    const float* __restrict__ W2,   const float* __restrict__ b2v,
    const _Float16* __restrict__ p2s, const _Float16* __restrict__ W1s,
    const _Float16* __restrict__ W2s,
    float* __restrict__ out)
{
    __shared__ __align__(16) char smem[SMEM_BYTES];
    _Float16* s_inv   = (_Float16*)(smem + OFF_INV);
    float*    s_red   = (float*)(smem + OFF_RED);
    float*    s_recip = (float*)(smem + OFF_RECIP);
    _Float16* s_X     = (_Float16*)smem;
    _Float16* s_H     = (_Float16*)smem;

    const int tid  = threadIdx.x;
    const int w    = tid >> 6;    // wave 0..3: owns c-rows [w*64, w*64+64) in phase A
    const int L    = tid & 63;
    const int quad = L >> 4;
    const int l16  = L & 15;

    // XCD swizzle: each XCD sees 2 batches -> p2s working set (1 MB) L2-resident
    const int id = blockIdx.x;
    const int b  = (id & 7) * 2 + ((id >> 3) & 1);
    const int n0 = (id >> 4) * TN;

    const float* __restrict__ z2b = xyz2 + (size_t)b * MPTS * 3;
    const float* __restrict__ p2b = p2   + (size_t)b * C2c * MPTS;
    // fragment base for this wave/lane: frags for (b, s, wt = w*4+ct)
    const _Float16* __restrict__ p2sb =
        F16P ? (p2s + (((size_t)b * 32 * 16 + (size_t)w * 4) * 64 + L) * 8) : (const _Float16*)nullptr;

    // inv-gen: thread owns query n = L, m-slice [s*32 + w*8, +8)
    const float x1x = xyz1[((size_t)b * NPTS + n0 + L) * 3 + 0];
    const float x1y = xyz1[((size_t)b * NPTS + n0 + L) * 3 + 1];
    const float x1z = xyz1[((size_t)b * NPTS + n0 + L) * 3 + 2];

    f32x4 acc[4][4];   // [ct][nt]: row c = w*64+ct*16+quad*4+r, col n = nt*16+l16
    #pragma unroll
    for (int ct = 0; ct < 4; ++ct)
        #pragma unroll
        for (int nt = 0; nt < 4; ++nt)
            acc[ct][nt] = (f32x4){0.f, 0.f, 0.f, 0.f};

    float ssum = 0.f;
    f16x8 Aa[2][4];

    auto loadA = [&](int s, f16x8 dst[4]) {
        if (F16P) {
            const _Float16* ap = p2sb + (size_t)s * (16 * 64 * 8);
            #pragma unroll
            for (int ct = 0; ct < 4; ++ct)
                dst[ct] = *(const f16x8*)(ap + (size_t)ct * (64 * 8));
        } else {
            const float* ap = p2b + (size_t)(w * 64 + l16) * MPTS + s * 32 + quad * 8;
            #pragma unroll
            for (int ct = 0; ct < 4; ++ct) {
                const float4 a0 = *(const float4*)(ap + (size_t)ct * (16 * MPTS));
                const float4 a1 = *(const float4*)(ap + (size_t)ct * (16 * MPTS) + 4);
                f16x8 h;
                h[0] = (_Float16)a0.x; h[1] = (_Float16)a0.y; h[2] = (_Float16)a0.z; h[3] = (_Float16)a0.w;
                h[4] = (_Float16)a1.x; h[5] = (_Float16)a1.y; h[6] = (_Float16)a1.z; h[7] = (_Float16)a1.w;
                dst[ct] = h;
            }
        }
    };

    auto gen = [&](int s) {
        const float* zp = z2b + (size_t)(s * 32 + w * 8) * 3;   // wave-uniform -> broadcast
        f32x4 zr[6];
        #pragma unroll
        for (int j = 0; j < 6; ++j) zr[j] = ((const f32x4*)zp)[j];
        const float* zv = (const float*)zr;
        f16x8 iv;
        #pragma unroll
        for (int i = 0; i < 8; ++i) {
            const float dx = x1x - zv[3 * i + 0];
            const float dy = x1y - zv[3 * i + 1];
            const float dz = x1z - zv[3 * i + 2];
            const float d2 = fmaf(dx, dx, fmaf(dy, dy, fmaf(dz, dz, 1e-12f)));
            const float inv = __builtin_amdgcn_rsqf(d2);
            ssum += inv;
            iv[i] = (_Float16)inv;
        }
        *(f16x8*)(s_inv + (s & 1) * (64 * LDI) + L * LDI + w * 8) = iv;
    };

    // preamble: A frags + inv for chunk 0
    loadA(0, Aa[0]);
    gen(0);
    __syncthreads();

    #pragma unroll 2
    for (int s = 0; s < 32; ++s) {
        const int cur = s & 1;
        if (s + 1 < 32) {
            loadA(s + 1, Aa[cur ^ 1]);   // contiguous L2 prefetch, covered by gen+MFMA
            gen(s + 1);                  // writes other inv buffer
        }
        const _Float16* bb = s_inv + cur * (64 * LDI) + l16 * LDI + quad * 8;
        #pragma unroll
        for (int nt = 0; nt < 4; ++nt) {
            const f16x8 bf = *(const f16x8*)(bb + nt * (16 * LDI));
            #pragma unroll
            for (int ct = 0; ct < 4; ++ct)
                acc[ct][nt] = __builtin_amdgcn_mfma_f32_16x16x32_f16(Aa[cur][ct], bf, acc[ct][nt], 0, 0, 0);
        }
        __syncthreads();   // inv(s) reads done; inv(s+1) writes visible
    }

    // ---- S[n] reduction over the 4 m-slice partials ----
    s_red[tid] = ssum;
    __syncthreads();
    if (tid < 64)
        s_recip[tid] = 1.0f / (s_red[tid] + s_red[tid + 64] + s_red[tid + 128] + s_red[tid + 192]);
    __syncthreads();   // s_recip ready; s_inv/s_red dead -> s_X overlay safe

    // interp -> s_X[n][128 + c]  (D rows = c: 4 consecutive c per reg quad)
    {
        float rn4[4];
        #pragma unroll
        for (int nt = 0; nt < 4; ++nt) rn4[nt] = s_recip[nt * 16 + l16];
        #pragma unroll
        for (int ct = 0; ct < 4; ++ct)
            #pragma unroll
            for (int nt = 0; nt < 4; ++nt) {
                const f32x4 v = acc[ct][nt];
                const float r = rn4[nt];
                f16x4 hv;
                hv[0] = (_Float16)(v[0] * r);
                hv[1] = (_Float16)(v[1] * r);
                hv[2] = (_Float16)(v[2] * r);
                hv[3] = (_Float16)(v[3] * r);
                *(f16x4*)(&s_X[(nt * 16 + l16) * LDXc + 128 + w * 64 + ct * 16 + quad * 4]) = hv;
            }
    }
    // p1 -> s_X[n][c], c in [0,128)
    {
        const float* p1b = p1 + (size_t)b * C1c * NPTS + n0;
        #pragma unroll
        for (int cc = 0; cc < 8; ++cc) {
            const int c = w * 32 + cc * 4;
            f16x4 v;
            v[0] = (_Float16)p1b[(size_t)(c + 0) * NPTS + L];
            v[1] = (_Float16)p1b[(size_t)(c + 1) * NPTS + L];
            v[2] = (_Float16)p1b[(size_t)(c + 2) * NPTS + L];
            v[3] = (_Float16)p1b[(size_t)(c + 3) * NPTS + L];
            *(f16x4*)(&s_X[L * LDXc + c]) = v;
        }
    }
    __syncthreads();   // x matrix complete

    // ---------------- Phase B: h = relu(W1 @ x + b1), K=384 ----------------
    f32x4 hacc[4][4];
    #pragma unroll
    for (int ct = 0; ct < 4; ++ct)
        #pragma unroll
        for (int nt = 0; nt < 4; ++nt)
            hacc[ct][nt] = (f32x4){0.f, 0.f, 0.f, 0.f};

    #pragma unroll 2
    for (int kc = 0; kc < 12; ++kc) {
        f16x8 af[4];
        if (F16P) {
            // frag u = ((w*4+ct)*12 + kc)*64 + L
            const _Float16* wp = W1s + (((size_t)(w * 4) * 12 + kc) * 64 + L) * 8;
            #pragma unroll
            for (int ct = 0; ct < 4; ++ct)
                af[ct] = *(const f16x8*)(wp + (size_t)ct * (12 * 64 * 8));
        } else {
            const float* wp = W1 + (size_t)(w * 64 + l16) * CINc + kc * 32 + quad * 8;
            #pragma unroll
            for (int ct = 0; ct < 4; ++ct) {
                const float4 a0 = *(const float4*)(wp + ct * (16 * CINc));
                const float4 a1 = *(const float4*)(wp + ct * (16 * CINc) + 4);
                f16x8 h;
                h[0] = (_Float16)a0.x; h[1] = (_Float16)a0.y; h[2] = (_Float16)a0.z; h[3] = (_Float16)a0.w;
                h[4] = (_Float16)a1.x; h[5] = (_Float16)a1.y; h[6] = (_Float16)a1.z; h[7] = (_Float16)a1.w;
                af[ct] = h;
            }
        }
        #pragma unroll
        for (int nt = 0; nt < 4; ++nt) {
            const f16x8 bf = *(const f16x8*)(&s_X[(nt * 16 + l16) * LDXc + kc * 32 + quad * 8]);
            #pragma unroll
            for (int ct = 0; ct < 4; ++ct)
                hacc[ct][nt] = __builtin_amdgcn_mfma_f32_16x16x32_f16(af[ct], bf, hacc[ct][nt], 0, 0, 0);
        }
    }

    __syncthreads();   // all s_X reads done before overlaying s_H

    // bias + relu + stage h -> s_H[n][o1]  (wave w owns o1 rows [w*64, +64))
    {
        f32x4 bb[4];
        #pragma unroll
        for (int ct = 0; ct < 4; ++ct)
            bb[ct] = *(const f32x4*)(b1v + w * 64 + ct * 16 + quad * 4);
        #pragma unroll
        for (int ct = 0; ct < 4; ++ct)
            #pragma unroll
            for (int nt = 0; nt < 4; ++nt) {
                const f32x4 v = hacc[ct][nt];
                f16x4 hv;
                hv[0] = (_Float16)fmaxf(v[0] + bb[ct][0], 0.f);
                hv[1] = (_Float16)fmaxf(v[1] + bb[ct][1], 0.f);
                hv[2] = (_Float16)fmaxf(v[2] + bb[ct][2], 0.f);
                hv[3] = (_Float16)fmaxf(v[3] + bb[ct][3], 0.f);
                *(f16x4*)(&s_H[(nt * 16 + l16) * LDH + w * 64 + ct * 16 + quad * 4]) = hv;
            }
    }
    __syncthreads();

    // ---------------- Phase C: out = relu(W2 @ h + b2), K=256 ----------------
    f32x4 oacc[2][4];
    #pragma unroll
    for (int ct = 0; ct < 2; ++ct)
        #pragma unroll
        for (int nt = 0; nt < 4; ++nt)
            oacc[ct][nt] = (f32x4){0.f, 0.f, 0.f, 0.f};

    #pragma unroll 2
    for (int oc = 0; oc < 8; ++oc) {
        f16x8 af2[2];
        if (F16P) {
            // frag v = ((w*2+ct)*8 + oc)*64 + L
            const _Float16* wp = W2s + (((size_t)(w * 2) * 8 + oc) * 64 + L) * 8;
            #pragma unroll
            for (int ct = 0; ct < 2; ++ct)
                af2[ct] = *(const f16x8*)(wp + (size_t)ct * (8 * 64 * 8));
        } else {
            const float* wp = W2 + (size_t)(w * 32 + l16) * H1c + oc * 32 + quad * 8;
            #pragma unroll
            for (int ct = 0; ct < 2; ++ct) {
                const float4 a0 = *(const float4*)(wp + ct * (16 * H1c));
                const float4 a1 = *(const float4*)(wp + ct * (16 * H1c) + 4);
                f16x8 h;
                h[0] = (_Float16)a0.x; h[1] = (_Float16)a0.y; h[2] = (_Float16)a0.z; h[3] = (_Float16)a0.w;
                h[4] = (_Float16)a1.x; h[5] = (_Float16)a1.y; h[6] = (_Float16)a1.z; h[7] = (_Float16)a1.w;
                af2[ct] = h;
            }
        }
        #pragma unroll
        for (int nt = 0; nt < 4; ++nt) {
            const f16x8 bf = *(const f16x8*)(&s_H[(nt * 16 + l16) * LDH + oc * 32 + quad * 8]);
            #pragma unroll
            for (int ct = 0; ct < 2; ++ct)
                oacc[ct][nt] = __builtin_amdgcn_mfma_f32_16x16x32_f16(af2[ct], bf, oacc[ct][nt], 0, 0, 0);
        }
    }

    // epilogue: bias + relu + store
    {
        f32x4 bb2[2];
        #pragma unroll
        for (int ct = 0; ct < 2; ++ct)
            bb2[ct] = *(const f32x4*)(b2v + w * 32 + ct * 16 + quad * 4);
        #pragma unroll
        for (int ct = 0; ct < 2; ++ct)
            #pragma unroll
            for (int nt = 0; nt < 4; ++nt) {
                float* op = out + ((size_t)b * H2c + w * 32 + ct * 16 + quad * 4) * NPTS
                                + n0 + nt * 16 + l16;
                #pragma unroll
                for (int j = 0; j < 4; ++j)
                    op[(size_t)j * NPTS] = fmaxf(oacc[ct][nt][j] + bb2[ct][j], 0.f);
            }
    }
}

extern "C" void kernel_launch(void* const* d_in, const int* in_sizes, int n_in,
                              void* d_out, int out_size, void* d_ws, size_t ws_size,
                              hipStream_t stream) {
    (void)in_sizes; (void)n_in; (void)out_size;
    const float* xyz1 = (const float*)d_in[0];
    const float* xyz2 = (const float*)d_in[1];
    const float* p1   = (const float*)d_in[2];
    const float* p2   = (const float*)d_in[3];
    const float* W1   = (const float*)d_in[4];
    const float* b1   = (const float*)d_in[5];
    const float* W2   = (const float*)d_in[6];
    const float* b2   = (const float*)d_in[7];
    float* out = (float*)d_out;

    const bool useh = (ws_size >= (size_t)WS_F16_TOTAL * 2);
    dim3 grid(BBATCH * (NPTS / TN));   // 1024 blocks
    dim3 block(256);
    if (useh) {
        _Float16* ws = (_Float16*)d_ws;
        const int nthr = NFRAG_P2 + NFRAG_W1 + NFRAG_W2;   // 540672 = 2112 * 256
        cvt_swz<<<dim3(nthr / 256), dim3(256), 0, stream>>>(p2, W1, W2, ws);
        fp_mfma6<true><<<grid, block, 0, stream>>>(xyz1, xyz2, p1, p2, W1, b1, W2, b2,
                                                   ws + WS_P2S, ws + WS_W1S, ws + WS_W2S, out);
    } else {
        fp_mfma6<false><<<grid, block, 0, stream>>>(xyz1, xyz2, p1, p2, W1, b1, W2, b2,
                                                    nullptr, nullptr, nullptr, out);
    }
}